// Round 9
// baseline (58.238 us; speedup 1.0000x reference)
//
#include <hip/hip_runtime.h>
#include <math.h>

// EnforceDecrease: persistent double-buffered pipeline.
//   ptps = wf.max(T) - wf.min(T); parent_min = min_P padded-ptps[parents];
//   resc = min(parent_min/ptps, 1); out0 = wf*resc; out1 = ptps*resc.
//
// R6: global_load_lds staging (74.5 -> 65.4 us).
// R8: nt stores (65.4 -> 55.8 us). FETCH unchanged => win was L2-level, not
//     L3 residency. HBM floor ~240MB/replay => ~38us ideal; gap = overlap.
// R9: persistent blocks (grid 1024 = 4/CU exact), 2x LDS waveform buffers.
//     Prefetch spike g+1 via DMA right after the top barrier; internal
//     barriers are raw s_barrier + lgkmcnt(0) ONLY (no vmcnt drain), so the
//     prefetch read stream overlaps the whole compute+store of spike g.

#define N_T 121
#define N_C 40
#define N_P 12
#define TPB 256
#define WF_ELEMS (N_T * N_C)               // 4840 floats
#define WF_QUADS (WF_ELEMS / 4)            // 1210 quads
#define FULL_K   (WF_QUADS / TPB)          // 4 full rounds
#define TAIL_Q   (WF_QUADS - FULL_K * TPB) // 186 tail quads
#define NBLK 1024                          // 4 blocks/CU, persistent
#define SPB  8                             // spikes per block (8192/1024)

typedef float f32x4 __attribute__((ext_vector_type(4)));

#define GLOAD_LDS16(g, l)                                              \
    __builtin_amdgcn_global_load_lds(                                  \
        (const __attribute__((address_space(1))) void*)(g),            \
        (__attribute__((address_space(3))) void*)(l), 16, 0, 0)

// Raw barrier: orders LDS (lgkmcnt) but leaves vmem (DMA prefetch + nt
// stores) in flight. "memory" clobber keeps LDS ops on the right side.
#define BAR_LGKM() do {                                                \
    asm volatile("s_waitcnt lgkmcnt(0)" ::: "memory");                 \
    __builtin_amdgcn_s_barrier();                                      \
} while (0)

__device__ __forceinline__ void stage(const float* __restrict__ src,
                                      float* dst, int tid) {
    #pragma unroll
    for (int k = 0; k < FULL_K; ++k) {
        const int q = tid + TPB * k;
        GLOAD_LDS16(src + 4 * q, dst + 4 * q);
    }
    if (tid < TAIL_Q) {
        const int q = FULL_K * TPB + tid;
        GLOAD_LDS16(src + 4 * q, dst + 4 * q);
    }
}

__global__ __launch_bounds__(TPB, 4) void enforce_decrease_kernel(
    const float* __restrict__ waveforms,
    const int*   __restrict__ max_channels,
    const int*   __restrict__ parents_index,
    float*       __restrict__ out,
    int n_total)
{
    // 2*19360 + 640 + 640 + 160 + 160 = 40320 B -> 40448 alloc, 4 blocks/CU.
    __shared__ float wf[2][WF_ELEMS];
    __shared__ float pmx[4 * N_C];
    __shared__ float pmn[4 * N_C];
    __shared__ float ptp[N_C];
    __shared__ float resc[N_C];

    const int tid = threadIdx.x;
    const int bid = blockIdx.x;

    // Prologue: stage first spike into buffer 0.
    stage(waveforms + (size_t)bid * WF_ELEMS, wf[0], tid);

    for (int g = 0; g < SPB; ++g) {
        const int    n    = bid + g * NBLK;
        float*       wcur = wf[g & 1];

        // Full drain: spike-n DMA landed in wcur; prior stores retired.
        __syncthreads();

        // Prefetch spike n+NBLK into the other buffer; stays in flight
        // across all raw barriers below (only drained at next top-sync).
        if (g + 1 < SPB)
            stage(waveforms + (size_t)(n + NBLK) * WF_ELEMS, wf[(g + 1) & 1], tid);

        // ---- Per-channel max/min, 4-way split over T (threads < 160).
        if (tid < 4 * N_C) {
            const int ch = tid % N_C;
            const int g4 = tid / N_C;
            float mx = -INFINITY, mn = INFINITY;
            for (int t = g4; t < N_T; t += 4) {
                const float v = wcur[t * N_C + ch];
                mx = fmaxf(mx, v);
                mn = fminf(mn, v);
            }
            pmx[tid] = mx;
            pmn[tid] = mn;
        }
        BAR_LGKM();

        // ---- Combine 4 partials -> ptp.
        if (tid < N_C) {
            float mx = pmx[tid], mn = pmn[tid];
            #pragma unroll
            for (int q = 1; q < 4; ++q) {
                mx = fmaxf(mx, pmx[q * N_C + tid]);
                mn = fminf(mn, pmn[q * N_C + tid]);
            }
            ptp[tid] = mx - mn;
        }
        BAR_LGKM();

        // ---- Parent gather + rescale + decreasing_ptps (nt store).
        if (tid < N_C) {
            const int  mc   = max_channels[n];
            const int* prow = parents_index + mc * (N_C * N_P) + tid * N_P;
            float minp = INFINITY;
            #pragma unroll
            for (int p = 0; p < N_P; ++p) {
                const int idx = prow[p];
                minp = fminf(minp, (idx >= N_C) ? INFINITY : ptp[idx]);
            }
            const float r = fminf(minp / ptp[tid], 1.0f);
            resc[tid] = r;
            __builtin_nontemporal_store(
                ptp[tid] * r,
                out + (size_t)n_total * WF_ELEMS + (size_t)n * N_C + tid);
        }
        BAR_LGKM();

        // ---- Scale + nt store (channels never wrap a quad: 40 % 4 == 0).
        const f32x4* w4   = (const f32x4*)wcur;
        f32x4*       dst4 = (f32x4*)(out + (size_t)n * WF_ELEMS);
        #pragma unroll
        for (int k = 0; k < FULL_K; ++k) {
            const int i = tid + TPB * k;
            f32x4 v = w4[i];
            const int ch0 = (i * 4) % N_C;
            v.x *= resc[ch0];
            v.y *= resc[ch0 + 1];
            v.z *= resc[ch0 + 2];
            v.w *= resc[ch0 + 3];
            __builtin_nontemporal_store(v, &dst4[i]);
        }
        if (tid < TAIL_Q) {
            const int i = FULL_K * TPB + tid;
            f32x4 v = w4[i];
            const int ch0 = (i * 4) % N_C;
            v.x *= resc[ch0];
            v.y *= resc[ch0 + 1];
            v.z *= resc[ch0 + 2];
            v.w *= resc[ch0 + 3];
            __builtin_nontemporal_store(v, &dst4[i]);
        }
    }
}

extern "C" void kernel_launch(void* const* d_in, const int* in_sizes, int n_in,
                              void* d_out, int out_size, void* d_ws, size_t ws_size,
                              hipStream_t stream) {
    const float* waveforms     = (const float*)d_in[0];
    const int*   max_channels  = (const int*)d_in[1];
    const int*   parents_index = (const int*)d_in[2];
    float*       out           = (float*)d_out;

    const int n = in_sizes[1];  // N = 8192

    enforce_decrease_kernel<<<dim3(NBLK), dim3(TPB), 0, stream>>>(
        waveforms, max_channels, parents_index, out, n);
}

// Round 10
// 56.128 us; speedup vs baseline: 1.0376x; 1.0376x over previous
//
#include <hip/hip_runtime.h>
#include <math.h>

// EnforceDecrease: persistent pipeline, counted-vmcnt top barrier.
//   ptps = wf.max(T) - wf.min(T); parent_min = min_P padded-ptps[parents];
//   resc = min(parent_min/ptps, 1); out0 = wf*resc; out1 = ptps*resc.
//
// R6: global_load_lds staging (74.5 -> 65.4 us).
// R8: nt stores (65.4 -> 55.8 us).
// R9: persistent dbuf @4 blk/CU, __syncthreads top drain: 58.2 us. Cause of
//     regression: vmcnt(0) at loop top waits the ~1210 nt-store ACKS every
//     iteration + occupancy halved.
// R10: TPB=512 (32 waves/CU, full occupancy) + uniform 3-DMA stage +
//      s_waitcnt vmcnt(2) top barrier: DMAs (issued a full iteration ago,
//      oldest in the in-order vmcnt queue) are guaranteed retired while the
//      newest stores stay in flight. Stores never block the pipeline.

#define N_T 121
#define N_C 40
#define N_P 12
#define TPB 512
#define NBLK 1024                      // 4 blocks/CU, persistent
#define SPB 8                          // spikes per block (8192/1024)
#define WF_ELEMS (N_T * N_C)           // 4840 floats
#define WF_QUADS (WF_ELEMS / 4)        // 1210 quads
#define TAIL_Q   (WF_QUADS - 2 * TPB)  // 186
#define ROW_F    4864                  // +6 quads pad for wave-2 spill lanes

typedef float f32x4 __attribute__((ext_vector_type(4)));

#define GLOAD_LDS16(g, l)                                              \
    __builtin_amdgcn_global_load_lds(                                  \
        (const __attribute__((address_space(1))) void*)(g),            \
        (__attribute__((address_space(3))) void*)(l), 16, 0, 0)

// Mid-loop barrier: order LDS only; prefetch DMA + stores stay in flight.
#define BAR_LGKM() do {                                                \
    asm volatile("s_waitcnt lgkmcnt(0)" ::: "memory");                 \
    __builtin_amdgcn_s_barrier();                                      \
} while (0)

// Uniform 3 DMA per thread. Round 2: threads >= TAIL_Q re-read quads
// (tid-186) -- L2-hot (just fetched by round 0), so ~no extra HBM traffic.
// Wave 2's lanes 58-63 land in the 6-quad LDS pad (HW dest = wave base +
// lane*16), never read back.
__device__ __forceinline__ void stage(const float* __restrict__ src,
                                      float* dst, int tid) {
    GLOAD_LDS16(src + 4 * tid,         dst + 4 * tid);
    GLOAD_LDS16(src + 4 * (TPB + tid), dst + 4 * (TPB + tid));
    const int q2 = (tid < TAIL_Q) ? (2 * TPB + tid) : (tid - TAIL_Q);
    GLOAD_LDS16(src + 4 * q2, dst + 4 * q2);
}

__global__ __launch_bounds__(TPB, 8) void enforce_decrease_kernel(
    const float* __restrict__ waveforms,
    const int*   __restrict__ max_channels,
    const int*   __restrict__ parents_index,
    float*       __restrict__ out,
    int n_total)
{
    // 2*4864*4 + 640 + 640 + 160 + 160 = 40512 B -> 4 blocks/CU.
    __shared__ float wf[2][ROW_F];
    __shared__ float pmx[4 * N_C];
    __shared__ float pmn[4 * N_C];
    __shared__ float ptp[N_C];
    __shared__ float resc[N_C];

    const int tid = threadIdx.x;
    const int bid = blockIdx.x;

    // Prologue: stage first spike into buffer 0.
    stage(waveforms + (size_t)bid * WF_ELEMS, wf[0], tid);

    for (int g = 0; g < SPB; ++g) {
        const int n    = bid + g * NBLK;
        float*    wcur = wf[g & 1];

        // Top barrier. Queue/wave (in issue order): [3 DMA][>=2 stores].
        // vmcnt(2): if the last DMA were pending, the >=2 younger stores
        // would also be pending (in-order retire) -> outstanding >=3 > 2.
        // So <=2 outstanding proves all DMA landed; newest stores may fly.
        if (g == 0)
            asm volatile("s_waitcnt vmcnt(0) lgkmcnt(0)" ::: "memory");
        else
            asm volatile("s_waitcnt vmcnt(2) lgkmcnt(0)" ::: "memory");
        __builtin_amdgcn_s_barrier();

        // Prefetch next spike into the other buffer; in flight across all
        // barriers below, waited only at the next top barrier.
        if (g + 1 < SPB)
            stage(waveforms + (size_t)(n + NBLK) * WF_ELEMS,
                  wf[(g + 1) & 1], tid);

        // ---- Per-channel max/min, 4-way split over T (threads < 160).
        if (tid < 4 * N_C) {
            const int ch = tid % N_C;
            const int g4 = tid / N_C;
            float mx = -INFINITY, mn = INFINITY;
            for (int t = g4; t < N_T; t += 4) {
                const float v = wcur[t * N_C + ch];
                mx = fmaxf(mx, v);
                mn = fminf(mn, v);
            }
            pmx[tid] = mx;
            pmn[tid] = mn;
        }
        BAR_LGKM();

        // ---- Combine 4 partials -> ptp.
        if (tid < N_C) {
            float mx = pmx[tid], mn = pmn[tid];
            #pragma unroll
            for (int q = 1; q < 4; ++q) {
                mx = fmaxf(mx, pmx[q * N_C + tid]);
                mn = fminf(mn, pmn[q * N_C + tid]);
            }
            ptp[tid] = mx - mn;
        }
        BAR_LGKM();

        // ---- Parent gather + rescale + decreasing_ptps (nt store, early
        // issue so it is long-retired by the next top vmcnt(2)).
        if (tid < N_C) {
            const int  mc   = max_channels[n];
            const int* prow = parents_index + mc * (N_C * N_P) + tid * N_P;
            float minp = INFINITY;
            #pragma unroll
            for (int p = 0; p < N_P; ++p) {
                const int idx = prow[p];
                minp = fminf(minp, (idx >= N_C) ? INFINITY : ptp[idx]);
            }
            const float r = fminf(minp / ptp[tid], 1.0f);
            resc[tid] = r;
            __builtin_nontemporal_store(
                ptp[tid] * r,
                out + (size_t)n_total * WF_ELEMS + (size_t)n * N_C + tid);
        }
        BAR_LGKM();

        // ---- Scale + nt stores (channels never wrap a quad: 40 % 4 == 0).
        // Tail store first so each wave's oldest scale-store has the
        // longest head start before the next top vmcnt(2).
        const f32x4* w4   = (const f32x4*)wcur;
        f32x4*       dst4 = (f32x4*)(out + (size_t)n * WF_ELEMS);
        if (tid < TAIL_Q) {
            const int i = 2 * TPB + tid;
            f32x4 v = w4[i];
            const int ch0 = (i * 4) % N_C;
            v.x *= resc[ch0];
            v.y *= resc[ch0 + 1];
            v.z *= resc[ch0 + 2];
            v.w *= resc[ch0 + 3];
            __builtin_nontemporal_store(v, &dst4[i]);
        }
        #pragma unroll
        for (int k = 0; k < 2; ++k) {
            const int i = tid + TPB * k;
            f32x4 v = w4[i];
            const int ch0 = (i * 4) % N_C;
            v.x *= resc[ch0];
            v.y *= resc[ch0 + 1];
            v.z *= resc[ch0 + 2];
            v.w *= resc[ch0 + 3];
            __builtin_nontemporal_store(v, &dst4[i]);
        }
    }
}

extern "C" void kernel_launch(void* const* d_in, const int* in_sizes, int n_in,
                              void* d_out, int out_size, void* d_ws, size_t ws_size,
                              hipStream_t stream) {
    const float* waveforms     = (const float*)d_in[0];
    const int*   max_channels  = (const int*)d_in[1];
    const int*   parents_index = (const int*)d_in[2];
    float*       out           = (float*)d_out;

    const int n = in_sizes[1];  // N = 8192

    enforce_decrease_kernel<<<dim3(NBLK), dim3(TPB), 0, stream>>>(
        waveforms, max_channels, parents_index, out, n);
}